// Round 11
// baseline (556.765 us; speedup 1.0000x reference)
//
#include <hip/hip_runtime.h>
#include <hip/hip_bf16.h>
#include <stdint.h>

typedef __attribute__((ext_vector_type(8))) short short8;
typedef __attribute__((ext_vector_type(4))) float floatx4;

#define MFMA32K(a, b, c) __builtin_amdgcn_mfma_f32_16x16x32_bf16(a, b, c, 0, 0, 0)

constexpr int N_Q  = 8192;
constexpr int M_KV = 8192;
constexpr int DMID = 128;
constexpr int DV   = 256;
constexpr int MWORDS = M_KV / 64;   // 128 u64 words per mask row

// fused preproc block-id ranges
constexpr int NB_PACK = N_Q * MWORDS / 256;   // 4096
constexpr int NB_PROJ = 256;                  // 128 x 2
constexpr int NB_VT   = 512;                  // 128 x 4

__device__ __forceinline__ unsigned short f2bf(float x) {
    unsigned u = __float_as_uint(x);
    u += 0x7fffu + ((u >> 16) & 1u);
    return (unsigned short)(u >> 16);
}

__device__ __forceinline__ short8 cvt_f8_bf8(float4 a, float4 b) {
    short8 r;
    r[0] = (short)f2bf(a.x); r[1] = (short)f2bf(a.y);
    r[2] = (short)f2bf(a.z); r[3] = (short)f2bf(a.w);
    r[4] = (short)f2bf(b.x); r[5] = (short)f2bf(b.y);
    r[6] = (short)f2bf(b.z); r[7] = (short)f2bf(b.w);
    return r;
}

// async global->LDS, 16B per lane; lds dst is wave-uniform (HW adds lane*16)
__device__ __forceinline__ void gl_lds16(const unsigned short* g, unsigned short* l) {
    __builtin_amdgcn_global_load_lds(
        (const __attribute__((address_space(1))) unsigned int*)g,
        (__attribute__((address_space(3))) unsigned int*)l, 16, 0, 0);
}

// nonzero-byte -> 4-bit mask (bit i = byte i != 0)
__device__ __forceinline__ unsigned nz4(unsigned x) {
    unsigned nz = (((x & 0x7f7f7f7fu) + 0x7f7f7f7fu) | x) & 0x80808080u;
    unsigned a = (nz >> 7) & 0x01010101u;
    return (a * 0x01020408u) >> 24;
}

// ---------------------------------------------------------------------------
// Fused preprocessing: one dispatch, three block-id ranges.
//   [0, NB_PACK)                 : bit-pack mask (dtype detected in-block)
//   [NB_PACK, NB_PACK+NB_PROJ)   : Q/K projections (bf16, unit-rotated rows)
//   [.., +NB_VT)                 : Vt build (pc-permuted + unit-rotated cols)
// All three are independent; fusing overlaps the HBM-bound pack with the
// compute-bound proj/vt and removes two kernel-launch serializations.
// ---------------------------------------------------------------------------
__global__ __launch_bounds__(256) void preproc_kernel(
    const float* __restrict__ main_feat, const float* __restrict__ other_feat,
    const float* __restrict__ fix_feat, const void* __restrict__ mask,
    const float* __restrict__ Wq, const float* __restrict__ bq,
    const float* __restrict__ Wk, const float* __restrict__ bk,
    unsigned short* __restrict__ Qw, unsigned short* __restrict__ Kw,
    unsigned short* __restrict__ Vt, unsigned long long* __restrict__ Mb)
{
    const int b = blockIdx.x;
    const int tid = threadIdx.x;
    const int wv = tid >> 6, lane = tid & 63;

    if (b < NB_PACK) {
        // ---------------- mask pack ----------------
        // in-block dtype detect: first 64 u32 words (L2-hot after block 0)
        unsigned w = ((const unsigned int*)mask)[lane];
        bool isf = (w == 0x3f800000u);
        bool isb = (w > 1u) && !isf;
        const int f = __ballot(isf) ? 2 : (__ballot(isb) ? 1 : 0);
        const int wbase = b * 256;

        if (f == 1) {   // uint8
            __shared__ unsigned short pbuf[1024];
            const uint4* g = (const uint4*)((const unsigned char*)mask + (size_t)wbase * 64);
#pragma unroll
            for (int r = 0; r < 4; ++r) {
                int p = wv * 256 + r * 64 + lane;
                uint4 v = g[p];
                unsigned m16 = nz4(v.x) | (nz4(v.y) << 4) | (nz4(v.z) << 8) | (nz4(v.w) << 12);
                pbuf[p] = (unsigned short)m16;
            }
            __syncthreads();
            Mb[wbase + tid] = ((const unsigned long long*)pbuf)[tid];
        } else {        // 32-bit elements (int32 or f32): ballot per word
            const unsigned int* mp = (const unsigned int*)mask;
            const int w0 = wbase + wv * 64;
#pragma unroll 4
            for (int i = 0; i < 64; ++i) {
                unsigned v = mp[(size_t)(w0 + i) * 64 + lane];
                unsigned long long bb = __ballot(v != 0u);
                if (lane == 0) Mb[w0 + i] = bb;
            }
        }
        return;
    }

    if (b < NB_PACK + NB_PROJ) {
        // ---------------- projections ----------------
        const int pb = b - NB_PACK;
        const int bx = pb & 127, by = pb >> 7;
        const float* src;  const float* W;  const float* bias;  unsigned short* dst;
        if (by == 0) { src = main_feat;  W = Wq; bias = bq; dst = Qw; }
        else         { src = other_feat; W = Wk; bias = bk; dst = Kw; }

        const int n = lane & 15, quad = lane >> 4;
        const int row0 = bx * 64 + wv * 16;

        short8 a[8];
        const float* ap = src + (size_t)(row0 + n) * 256 + quad * 8;
#pragma unroll
        for (int ks = 0; ks < 8; ++ks) {
            float4 x0 = *(const float4*)(ap + ks * 32);
            float4 x1 = *(const float4*)(ap + ks * 32 + 4);
            a[ks] = cvt_f8_bf8(x0, x1);
        }

        floatx4 acc[8];
#pragma unroll
        for (int nt = 0; nt < 8; ++nt) acc[nt] = floatx4{0.f, 0.f, 0.f, 0.f};

#pragma unroll
        for (int nt = 0; nt < 8; ++nt) {
            const float* wp = W + (size_t)(nt * 16 + n) * 256 + quad * 8;
#pragma unroll
            for (int ks = 0; ks < 8; ++ks) {
                float4 w0 = *(const float4*)(wp + ks * 32);
                float4 w1 = *(const float4*)(wp + ks * 32 + 4);
                short8 bb = cvt_f8_bf8(w0, w1);
                acc[nt] = MFMA32K(a[ks], bb, acc[nt]);
            }
        }

#pragma unroll
        for (int nt = 0; nt < 8; ++nt) {
            float bb = bias[nt * 16 + n];
#pragma unroll
            for (int reg = 0; reg < 4; ++reg) {
                int r = row0 + quad * 4 + reg;
                int c = nt * 16 + n;
                int phys = ((((c >> 3) + r) & 15) << 3) | (c & 7);
                dst[(size_t)r * DMID + phys] = f2bf(acc[nt][reg] + bb);
            }
        }
        return;
    }

    // ---------------- Vt build ----------------
    {
        __shared__ unsigned short tile[64 * 72];
        const int vb = b - NB_PACK - NB_PROJ;
        const int m0 = (vb & 127) * 64, d0 = (vb >> 7) * 64;

#pragma unroll
        for (int r = 0; r < 4; ++r) {
            int idx = r * 256 + tid;
            int ml = idx >> 4, dl4 = (idx & 15) * 4;
            float4 v = *(const float4*)(other_feat + (size_t)(m0 + ml) * 256 + d0 + dl4);
            float f = fix_feat[m0 + ml];
            tile[(dl4 + 0) * 72 + ml] = f2bf(v.x * f);
            tile[(dl4 + 1) * 72 + ml] = f2bf(v.y * f);
            tile[(dl4 + 2) * 72 + ml] = f2bf(v.z * f);
            tile[(dl4 + 3) * 72 + ml] = f2bf(v.w * f);
        }
        __syncthreads();
#pragma unroll
        for (int r = 0; r < 8; ++r) {
            int dl = r * 8 + (tid >> 5);
            int d = d0 + dl;
            int ml = (tid & 31) * 2;
            int e = ml >> 5, s = (ml >> 4) & 1, q = (ml >> 2) & 3, j = ml & 3;
            int pc = e * 32 + q * 8 + s * 4 + j;
            int phys = ((((pc >> 3) + d) & 7) << 3) | (pc & 7);
            unsigned int v0 = tile[dl * 72 + ml];
            unsigned int v1 = tile[dl * 72 + ml + 1];
            *(unsigned int*)(Vt + (size_t)d * M_KV + m0 + phys) = v0 | (v1 << 16);
        }
    }
}

// ---------------------------------------------------------------------------
// Flash attention (R7-best config, verbatim): BM=128, K double-buffered,
// Vt single-buffered software pipeline, S^T formulation, all-16x16x32 MFMA,
// pc-permuted Vt, no online max. LDS = 64 KB -> 2 blocks/CU.
// ---------------------------------------------------------------------------
__global__ __launch_bounds__(256, 2) void flash_kernel(
    const unsigned short* __restrict__ Qw, const unsigned short* __restrict__ Kw,
    const unsigned short* __restrict__ Vt, const unsigned long long* __restrict__ Mb,
    unsigned short* __restrict__ Opart, float* __restrict__ Lpart,
    int nsplit, int lgNs)
{
    __shared__ __align__(16) unsigned short k_lds[2][64 * 128];  // 2 x 16 KB
    __shared__ __align__(16) unsigned short vt_lds[256 * 64];    // 32 KB

    const int L = blockIdx.x + gridDim.x * blockIdx.y;
    const int ly = L & (nsplit - 1);
    const int lx = L >> lgNs;
    const int chunkLen = M_KV >> lgNs;
    const int mBeg = ly * chunkLen;
    const int tid = threadIdx.x;
    const int wave = tid >> 6, lane = tid & 63, n = lane & 15, quad = lane >> 4;
    const int qrow0 = lx * 128 + wave * 32;
    constexpr float SC = 0.08838834764831845f * 1.4426950408889634f; // scale*log2(e)

    // Q fragments (rotated layout: unit' = (unit + row) & 15)
    short8 qf[2][4];
#pragma unroll
    for (int qt = 0; qt < 2; ++qt)
#pragma unroll
        for (int db = 0; db < 4; ++db) {
            int row = qrow0 + qt * 16 + n;
            int phys = (db * 4 + quad + row) & 15;
            qf[qt][db] = *(const short8*)(Qw + (size_t)row * DMID + phys * 8);
        }

    floatx4 Oacc[2][16];
#pragma unroll
    for (int qt = 0; qt < 2; ++qt)
#pragma unroll
        for (int dt = 0; dt < 16; ++dt) Oacc[qt][dt] = floatx4{0.f, 0.f, 0.f, 0.f};

    float lrow[2] = {0.f, 0.f};

    // staging invariants
    const unsigned short* kg = Kw + (size_t)(wave * 4 + (lane >> 4)) * DMID + (lane & 15) * 8;
    const unsigned short* vg = Vt + (size_t)(wave * 8 + (lane >> 3)) * M_KV + (lane & 7) * 8;
    unsigned short* vld = &vt_lds[wave * 512];
    const int kqn = quad + n;

    // prologue: K(0) DMA into buffer 0
#pragma unroll
    for (int r = 0; r < 4; ++r)
        gl_lds16(kg + (size_t)(mBeg + r * 16) * DMID, &k_lds[0][wave * 512 + r * 2048]);

    const int iters = chunkLen / 64;
    for (int it = 0; it < iters; ++it) {
        const int m0 = mBeg + it * 64;
        const unsigned short* kbuf = k_lds[it & 1];

        __syncthreads();   // drains K(it); separates PV(it-1) reads from Vt(it) writes

        // Vt(it) DMA (drained at mid barrier; overlaps QK+softmax)
#pragma unroll
        for (int r = 0; r < 8; ++r)
            gl_lds16(vg + (size_t)(r * 32) * M_KV + m0, vld + r * 2048);

        // mask words
        unsigned long long wbits[2];
#pragma unroll
        for (int qt = 0; qt < 2; ++qt)
            wbits[qt] = Mb[(size_t)(qrow0 + qt * 16 + n) * MWORDS + (m0 >> 6)];

        // ---- S^T = K Q^T (kv = 16kvt + 4quad + reg, q = n) ----
        floatx4 ST[4][2];
#pragma unroll
        for (int kvt = 0; kvt < 4; ++kvt) {
            const int rowoff = (kvt * 16 + n) * DMID;
            short8 a0 = *(const short8*)&kbuf[rowoff + (((kqn + 0) & 15) << 3)];
            short8 a1 = *(const short8*)&kbuf[rowoff + (((kqn + 4) & 15) << 3)];
            short8 a2 = *(const short8*)&kbuf[rowoff + (((kqn + 8) & 15) << 3)];
            short8 a3 = *(const short8*)&kbuf[rowoff + (((kqn + 12) & 15) << 3)];
#pragma unroll
            for (int qt = 0; qt < 2; ++qt) {
                floatx4 s = floatx4{0.f, 0.f, 0.f, 0.f};
                s = MFMA32K(a0, qf[qt][0], s);
                s = MFMA32K(a1, qf[qt][1], s);
                s = MFMA32K(a2, qf[qt][2], s);
                s = MFMA32K(a3, qf[qt][3], s);
                ST[kvt][qt] = s;
            }
        }

        // ---- p = exp2(s*SC), 0 where masked; pack to A-frags ----
        short8 pf8[2][2];
#pragma unroll
        for (int qt = 0; qt < 2; ++qt) {
            unsigned long long x = wbits[qt] >> (quad * 4);
            float lacc = 0.f;
#pragma unroll
            for (int kvt = 0; kvt < 4; ++kvt) {
                int e = kvt >> 1, s = kvt & 1;
                float p[4];
#pragma unroll
                for (int j = 0; j < 4; ++j) {
                    float v = __builtin_amdgcn_exp2f(ST[kvt][qt][j] * SC);
                    p[j] = ((x >> (kvt * 16 + j)) & 1ull) ? 0.f : v;
                    lacc += p[j];
                }
                __hip_bfloat162 h0 = __float22bfloat162_rn(make_float2(p[0], p[1]));
                __hip_bfloat162 h1 = __float22bfloat162_rn(make_float2(p[2], p[3]));
                unsigned u0, u1;
                __builtin_memcpy(&u0, &h0, 4);
                __builtin_memcpy(&u1, &h1, 4);
                ((unsigned*)&pf8[qt][e])[s * 2 + 0] = u0;
                ((unsigned*)&pf8[qt][e])[s * 2 + 1] = u1;
            }
            lrow[qt] += lacc;
        }

        __syncthreads();   // drains Vt(it); separates QK reads from K(it+1) writes

        // K(it+1) DMA into other buffer
        if (it + 1 < iters) {
            unsigned short* knext = (unsigned short*)&k_lds[(it + 1) & 1][wave * 512];
#pragma unroll
            for (int r = 0; r < 4; ++r)
                gl_lds16(kg + (size_t)(m0 + 64 + r * 16) * DMID, knext + r * 2048);
        }

        // ---- O += P V (rotated contiguous b128 from vt_lds) ----
#pragma unroll
        for (int e = 0; e < 2; ++e) {
#pragma unroll
            for (int dt = 0; dt < 16; ++dt) {
                const int vb = (dt * 16 + n) * 64 + (((e * 4 + quad + n) & 7) << 3);
                short8 bv = *(const short8*)&vt_lds[vb];
                Oacc[0][dt] = MFMA32K(pf8[0][e], bv, Oacc[0][dt]);
                Oacc[1][dt] = MFMA32K(pf8[1][e], bv, Oacc[1][dt]);
            }
        }
    }

    // ---- epilogue: bf16 partials + cross-quad l reduction ----
    const size_t obase = (size_t)ly * N_Q * DV;
#pragma unroll
    for (int qt = 0; qt < 2; ++qt)
#pragma unroll
        for (int dt = 0; dt < 16; ++dt)
#pragma unroll
            for (int reg = 0; reg < 4; ++reg) {
                int gr = qrow0 + qt * 16 + quad * 4 + reg;
                Opart[obase + (size_t)gr * DV + dt * 16 + n] = f2bf(Oacc[qt][dt][reg]);
            }
#pragma unroll
    for (int qt = 0; qt < 2; ++qt) {
        float r = lrow[qt];
        r += __shfl_xor(r, 16);
        r += __shfl_xor(r, 32);
        if (quad == 0)
            Lpart[ly * N_Q + qrow0 + qt * 16 + n] = r;
    }
}

// ---------------------------------------------------------------------------
// Combine: out = (sum_c O_c) / (sum_c l_c).
// ---------------------------------------------------------------------------
__global__ __launch_bounds__(256) void combine_kernel(
    const unsigned short* __restrict__ Opart, const float* __restrict__ Lpart,
    float* __restrict__ out, int nsplit)
{
    const int row = blockIdx.x, d = threadIdx.x;
    float L = 0.f, o = 0.f;
    for (int c = 0; c < nsplit; ++c) {
        L += Lpart[c * N_Q + row];
        unsigned int b = Opart[((size_t)c * N_Q + row) * DV + d];
        o += __uint_as_float(b << 16);
    }
    out[(size_t)row * DV + d] = o / L;
}

// ---------------------------------------------------------------------------
extern "C" void kernel_launch(void* const* d_in, const int* in_sizes, int n_in,
                              void* d_out, int out_size, void* d_ws, size_t ws_size,
                              hipStream_t stream)
{
    const float* main_feat  = (const float*)d_in[0];
    const float* other_feat = (const float*)d_in[1];
    const float* fix_feat   = (const float*)d_in[2];
    const void*  mask       = d_in[3];
    const float* Wq         = (const float*)d_in[4];
    const float* bq         = (const float*)d_in[5];
    const float* Wk         = (const float*)d_in[6];
    const float* bk         = (const float*)d_in[7];
    float* out = (float*)d_out;

    char* ws = (char*)d_ws;
    unsigned short* Qw = (unsigned short*)(ws);                         // 2 MB
    unsigned short* Kw = (unsigned short*)(ws + (1ull << 21));          // 2 MB
    unsigned short* Vt = (unsigned short*)(ws + (2ull << 21));          // 4 MB
    unsigned long long* Mb = (unsigned long long*)(ws + (8ull << 20) + 1024);  // 8 MB
    float* Lpart = (float*)(ws + (16ull << 20) + 2048);

    const size_t base = (16ull << 20) + 2048;
    auto need = [&](int ns) {
        return base + (size_t)ns * N_Q * 4 + (size_t)ns * N_Q * DV * 2;
    };
    int nsplit = 1, lgNs = 0;
    if (ws_size >= need(8))      { nsplit = 8; lgNs = 3; }
    else if (ws_size >= need(4)) { nsplit = 4; lgNs = 2; }
    else if (ws_size >= need(2)) { nsplit = 2; lgNs = 1; }

    unsigned short* Opart = (unsigned short*)(Lpart + (size_t)nsplit * N_Q);

    hipLaunchKernelGGL(preproc_kernel, dim3(NB_PACK + NB_PROJ + NB_VT), dim3(256), 0, stream,
                       main_feat, other_feat, fix_feat, mask,
                       Wq, bq, Wk, bk, Qw, Kw, Vt, Mb);
    hipLaunchKernelGGL(flash_kernel, dim3(64, nsplit), dim3(256), 0, stream,
                       Qw, Kw, Vt, Mb, Opart, Lpart, nsplit, lgNs);
    hipLaunchKernelGGL(combine_kernel, dim3(N_Q), dim3(256), 0, stream,
                       Opart, Lpart, out, nsplit);
}

// Round 12
// 475.292 us; speedup vs baseline: 1.1714x; 1.1714x over previous
//
#include <hip/hip_runtime.h>
#include <hip/hip_bf16.h>
#include <stdint.h>

typedef __attribute__((ext_vector_type(8))) short short8;
typedef __attribute__((ext_vector_type(4))) float floatx4;

#define MFMA32K(a, b, c) __builtin_amdgcn_mfma_f32_16x16x32_bf16(a, b, c, 0, 0, 0)

constexpr int N_Q  = 8192;
constexpr int M_KV = 8192;
constexpr int DMID = 128;
constexpr int DV   = 256;
constexpr int MWORDS = M_KV / 64;   // 128 u64 words per mask row

__device__ __forceinline__ unsigned short f2bf(float x) {
    unsigned u = __float_as_uint(x);
    u += 0x7fffu + ((u >> 16) & 1u);
    return (unsigned short)(u >> 16);
}

__device__ __forceinline__ short8 cvt_f8_bf8(float4 a, float4 b) {
    short8 r;
    r[0] = (short)f2bf(a.x); r[1] = (short)f2bf(a.y);
    r[2] = (short)f2bf(a.z); r[3] = (short)f2bf(a.w);
    r[4] = (short)f2bf(b.x); r[5] = (short)f2bf(b.y);
    r[6] = (short)f2bf(b.z); r[7] = (short)f2bf(b.w);
    return r;
}

// async global->LDS, 16B per lane; lds dst is wave-uniform (HW adds lane*16)
__device__ __forceinline__ void gl_lds16(const unsigned short* g, unsigned short* l) {
    __builtin_amdgcn_global_load_lds(
        (const __attribute__((address_space(1))) unsigned int*)g,
        (__attribute__((address_space(3))) unsigned int*)l, 16, 0, 0);
}

// nonzero-byte -> 4-bit mask (bit i = byte i != 0)
__device__ __forceinline__ unsigned nz4(unsigned x) {
    unsigned nz = (((x & 0x7f7f7f7fu) + 0x7f7f7f7fu) | x) & 0x80808080u;
    unsigned a = (nz >> 7) & 0x01010101u;
    return (a * 0x01020408u) >> 24;
}

// 4 bytes, each holding a nibble in its low 4 bits -> packed 16 bits
__device__ __forceinline__ unsigned nib4_to_16(unsigned x) {
    unsigned t = x | (x >> 4);
    return (t & 0xFFu) | ((t >> 8) & 0xFF00u);
}

// ---------------------------------------------------------------------------
// Pack mask -> 1 bit per element. Dtype detected in-block (2 ballots on the
// first 64 words, L2-hot).
// int32/f32 path (the measured dtype): 16 independent uint4 loads per thread
// (256 B coalesced, deep MLP -> HBM-BW-bound), nonzero-nibbles staged in LDS,
// each thread then assembles one u64 word from 16 contiguous nibble bytes.
// No ballots, no per-iteration vmcnt waits.
// ---------------------------------------------------------------------------
__global__ __launch_bounds__(256) void pack_mask_kernel(
    const void* __restrict__ mask, unsigned long long* __restrict__ Mb)
{
    const int tid = threadIdx.x;
    const int wv = tid >> 6, lane = tid & 63;
    const int wbase = blockIdx.x * 256;

    // in-block dtype detect
    unsigned w0 = ((const unsigned int*)mask)[lane];
    bool isf = (w0 == 0x3f800000u);
    bool isb = (w0 > 1u) && !isf;
    const int f = __ballot(isf) ? 2 : (__ballot(isb) ? 1 : 0);

    if (f == 1) {   // uint8
        __shared__ unsigned short pbuf[1024];
        const uint4* g = (const uint4*)((const unsigned char*)mask + (size_t)wbase * 64);
#pragma unroll
        for (int r = 0; r < 4; ++r) {
            int p = wv * 256 + r * 64 + lane;
            uint4 v = g[p];
            unsigned m16 = nz4(v.x) | (nz4(v.y) << 4) | (nz4(v.z) << 8) | (nz4(v.w) << 12);
            pbuf[p] = (unsigned short)m16;
        }
        __syncthreads();
        Mb[wbase + tid] = ((const unsigned long long*)pbuf)[tid];
    } else {
        // 32-bit elements (int32 or f32 {0,1}): nonzero test on raw bits.
        // Block covers 16384 elements = 64 KB. 16 uint4 loads per thread.
        __shared__ unsigned char nib[4096];   // nib[idx4], idx4 = r*256+tid
        const uint4* g = (const uint4*)mask + (size_t)wbase * 16;
        uint4 v[16];
#pragma unroll
        for (int r = 0; r < 16; ++r) v[r] = g[r * 256 + tid];   // independent -> deep MLP
#pragma unroll
        for (int r = 0; r < 16; ++r) {
            unsigned nb = (unsigned)(v[r].x != 0u)
                        | ((unsigned)(v[r].y != 0u) << 1)
                        | ((unsigned)(v[r].z != 0u) << 2)
                        | ((unsigned)(v[r].w != 0u) << 3);
            nib[r * 256 + tid] = (unsigned char)nb;
        }
        __syncthreads();
        // word tid covers nibbles idx4 = tid*16 .. +15 (16 contiguous bytes)
        uint4 nv = *(const uint4*)&nib[tid * 16];
        unsigned long long out =
              (unsigned long long)nib4_to_16(nv.x)
            | ((unsigned long long)nib4_to_16(nv.y) << 16)
            | ((unsigned long long)nib4_to_16(nv.z) << 32)
            | ((unsigned long long)nib4_to_16(nv.w) << 48);
        Mb[wbase + tid] = out;
    }
}

// ---------------------------------------------------------------------------
// Projections: dst[row] = src[row] @ W^T + bias, bf16, 16B-unit rotation
// within the row: unit' = (unit + row) & 15.
// ---------------------------------------------------------------------------
__global__ __launch_bounds__(256) void proj_kernel(
    const float* __restrict__ main_feat, const float* __restrict__ Wq, const float* __restrict__ bq,
    const float* __restrict__ other_feat, const float* __restrict__ Wk, const float* __restrict__ bk,
    unsigned short* __restrict__ Qw, unsigned short* __restrict__ Kw)
{
    const float* src;  const float* W;  const float* bias;  unsigned short* dst;
    if (blockIdx.y == 0) { src = main_feat;  W = Wq; bias = bq; dst = Qw; }
    else                 { src = other_feat; W = Wk; bias = bk; dst = Kw; }

    const int wave = threadIdx.x >> 6, lane = threadIdx.x & 63;
    const int n = lane & 15, quad = lane >> 4;
    const int row0 = blockIdx.x * 64 + wave * 16;

    short8 a[8];
    const float* ap = src + (size_t)(row0 + n) * 256 + quad * 8;
#pragma unroll
    for (int ks = 0; ks < 8; ++ks) {
        float4 x0 = *(const float4*)(ap + ks * 32);
        float4 x1 = *(const float4*)(ap + ks * 32 + 4);
        a[ks] = cvt_f8_bf8(x0, x1);
    }

    floatx4 acc[8];
#pragma unroll
    for (int nt = 0; nt < 8; ++nt) acc[nt] = floatx4{0.f, 0.f, 0.f, 0.f};

#pragma unroll
    for (int nt = 0; nt < 8; ++nt) {
        const float* wp = W + (size_t)(nt * 16 + n) * 256 + quad * 8;
#pragma unroll
        for (int ks = 0; ks < 8; ++ks) {
            float4 w0 = *(const float4*)(wp + ks * 32);
            float4 w1 = *(const float4*)(wp + ks * 32 + 4);
            short8 b = cvt_f8_bf8(w0, w1);
            acc[nt] = MFMA32K(a[ks], b, acc[nt]);
        }
    }

#pragma unroll
    for (int nt = 0; nt < 8; ++nt) {
        float bb = bias[nt * 16 + n];
#pragma unroll
        for (int reg = 0; reg < 4; ++reg) {
            int r = row0 + quad * 4 + reg;
            int c = nt * 16 + n;
            int phys = ((((c >> 3) + r) & 15) << 3) | (c & 7);
            dst[(size_t)r * DMID + phys] = f2bf(acc[nt][reg] + bb);
        }
    }
}

// ---------------------------------------------------------------------------
// Vt[d][col(m)] = fix[m] * other[m][d]; col = pc-permutation (kv=32e+16s+4q+j
// -> pc=32e+8q+4s+j) composed with 16B-unit rotation by d per 64-col group.
// ---------------------------------------------------------------------------
__global__ __launch_bounds__(256) void build_vt_kernel(
    const float* __restrict__ other_feat, const float* __restrict__ fix_feat,
    unsigned short* __restrict__ Vt)
{
    __shared__ unsigned short tile[64 * 72];
    const int t = threadIdx.x;
    const int m0 = blockIdx.x * 64, d0 = blockIdx.y * 64;

#pragma unroll
    for (int r = 0; r < 4; ++r) {
        int idx = r * 256 + t;
        int ml = idx >> 4, dl4 = (idx & 15) * 4;
        float4 v = *(const float4*)(other_feat + (size_t)(m0 + ml) * 256 + d0 + dl4);
        float f = fix_feat[m0 + ml];
        tile[(dl4 + 0) * 72 + ml] = f2bf(v.x * f);
        tile[(dl4 + 1) * 72 + ml] = f2bf(v.y * f);
        tile[(dl4 + 2) * 72 + ml] = f2bf(v.z * f);
        tile[(dl4 + 3) * 72 + ml] = f2bf(v.w * f);
    }
    __syncthreads();
#pragma unroll
    for (int r = 0; r < 8; ++r) {
        int dl = r * 8 + (t >> 5);
        int d = d0 + dl;
        int ml = (t & 31) * 2;
        int e = ml >> 5, s = (ml >> 4) & 1, q = (ml >> 2) & 3, j = ml & 3;
        int pc = e * 32 + q * 8 + s * 4 + j;
        int phys = ((((pc >> 3) + d) & 7) << 3) | (pc & 7);
        unsigned int v0 = tile[dl * 72 + ml];
        unsigned int v1 = tile[dl * 72 + ml + 1];
        *(unsigned int*)(Vt + (size_t)d * M_KV + m0 + phys) = v0 | (v1 << 16);
    }
}

// ---------------------------------------------------------------------------
// Flash attention (R7-best config, verbatim): BM=128, K double-buffered,
// Vt single-buffered software pipeline, S^T formulation, all-16x16x32 MFMA,
// pc-permuted Vt, no online max. LDS = 64 KB -> 2 blocks/CU.
// ---------------------------------------------------------------------------
__global__ __launch_bounds__(256, 2) void flash_kernel(
    const unsigned short* __restrict__ Qw, const unsigned short* __restrict__ Kw,
    const unsigned short* __restrict__ Vt, const unsigned long long* __restrict__ Mb,
    unsigned short* __restrict__ Opart, float* __restrict__ Lpart,
    int nsplit, int lgNs)
{
    __shared__ __align__(16) unsigned short k_lds[2][64 * 128];  // 2 x 16 KB
    __shared__ __align__(16) unsigned short vt_lds[256 * 64];    // 32 KB

    const int L = blockIdx.x + gridDim.x * blockIdx.y;
    const int ly = L & (nsplit - 1);
    const int lx = L >> lgNs;
    const int chunkLen = M_KV >> lgNs;
    const int mBeg = ly * chunkLen;
    const int tid = threadIdx.x;
    const int wave = tid >> 6, lane = tid & 63, n = lane & 15, quad = lane >> 4;
    const int qrow0 = lx * 128 + wave * 32;
    constexpr float SC = 0.08838834764831845f * 1.4426950408889634f; // scale*log2(e)

    // Q fragments (rotated layout: unit' = (unit + row) & 15)
    short8 qf[2][4];
#pragma unroll
    for (int qt = 0; qt < 2; ++qt)
#pragma unroll
        for (int db = 0; db < 4; ++db) {
            int row = qrow0 + qt * 16 + n;
            int phys = (db * 4 + quad + row) & 15;
            qf[qt][db] = *(const short8*)(Qw + (size_t)row * DMID + phys * 8);
        }

    floatx4 Oacc[2][16];
#pragma unroll
    for (int qt = 0; qt < 2; ++qt)
#pragma unroll
        for (int dt = 0; dt < 16; ++dt) Oacc[qt][dt] = floatx4{0.f, 0.f, 0.f, 0.f};

    float lrow[2] = {0.f, 0.f};

    // staging invariants
    const unsigned short* kg = Kw + (size_t)(wave * 4 + (lane >> 4)) * DMID + (lane & 15) * 8;
    const unsigned short* vg = Vt + (size_t)(wave * 8 + (lane >> 3)) * M_KV + (lane & 7) * 8;
    unsigned short* vld = &vt_lds[wave * 512];
    const int kqn = quad + n;

    // prologue: K(0) DMA into buffer 0
#pragma unroll
    for (int r = 0; r < 4; ++r)
        gl_lds16(kg + (size_t)(mBeg + r * 16) * DMID, &k_lds[0][wave * 512 + r * 2048]);

    const int iters = chunkLen / 64;
    for (int it = 0; it < iters; ++it) {
        const int m0 = mBeg + it * 64;
        const unsigned short* kbuf = k_lds[it & 1];

        __syncthreads();   // drains K(it); separates PV(it-1) reads from Vt(it) writes

        // Vt(it) DMA (drained at mid barrier; overlaps QK+softmax)
#pragma unroll
        for (int r = 0; r < 8; ++r)
            gl_lds16(vg + (size_t)(r * 32) * M_KV + m0, vld + r * 2048);

        // mask words
        unsigned long long wbits[2];
#pragma unroll
        for (int qt = 0; qt < 2; ++qt)
            wbits[qt] = Mb[(size_t)(qrow0 + qt * 16 + n) * MWORDS + (m0 >> 6)];

        // ---- S^T = K Q^T (kv = 16kvt + 4quad + reg, q = n) ----
        floatx4 ST[4][2];
#pragma unroll
        for (int kvt = 0; kvt < 4; ++kvt) {
            const int rowoff = (kvt * 16 + n) * DMID;
            short8 a0 = *(const short8*)&kbuf[rowoff + (((kqn + 0) & 15) << 3)];
            short8 a1 = *(const short8*)&kbuf[rowoff + (((kqn + 4) & 15) << 3)];
            short8 a2 = *(const short8*)&kbuf[rowoff + (((kqn + 8) & 15) << 3)];
            short8 a3 = *(const short8*)&kbuf[rowoff + (((kqn + 12) & 15) << 3)];
#pragma unroll
            for (int qt = 0; qt < 2; ++qt) {
                floatx4 s = floatx4{0.f, 0.f, 0.f, 0.f};
                s = MFMA32K(a0, qf[qt][0], s);
                s = MFMA32K(a1, qf[qt][1], s);
                s = MFMA32K(a2, qf[qt][2], s);
                s = MFMA32K(a3, qf[qt][3], s);
                ST[kvt][qt] = s;
            }
        }

        // ---- p = exp2(s*SC), 0 where masked; pack to A-frags ----
        short8 pf8[2][2];
#pragma unroll
        for (int qt = 0; qt < 2; ++qt) {
            unsigned long long x = wbits[qt] >> (quad * 4);
            float lacc = 0.f;
#pragma unroll
            for (int kvt = 0; kvt < 4; ++kvt) {
                int e = kvt >> 1, s = kvt & 1;
                float p[4];
#pragma unroll
                for (int j = 0; j < 4; ++j) {
                    float v = __builtin_amdgcn_exp2f(ST[kvt][qt][j] * SC);
                    p[j] = ((x >> (kvt * 16 + j)) & 1ull) ? 0.f : v;
                    lacc += p[j];
                }
                __hip_bfloat162 h0 = __float22bfloat162_rn(make_float2(p[0], p[1]));
                __hip_bfloat162 h1 = __float22bfloat162_rn(make_float2(p[2], p[3]));
                unsigned u0, u1;
                __builtin_memcpy(&u0, &h0, 4);
                __builtin_memcpy(&u1, &h1, 4);
                ((unsigned*)&pf8[qt][e])[s * 2 + 0] = u0;
                ((unsigned*)&pf8[qt][e])[s * 2 + 1] = u1;
            }
            lrow[qt] += lacc;
        }

        __syncthreads();   // drains Vt(it); separates QK reads from K(it+1) writes

        // K(it+1) DMA into other buffer
        if (it + 1 < iters) {
            unsigned short* knext = (unsigned short*)&k_lds[(it + 1) & 1][wave * 512];
#pragma unroll
            for (int r = 0; r < 4; ++r)
                gl_lds16(kg + (size_t)(m0 + 64 + r * 16) * DMID, knext + r * 2048);
        }

        // ---- O += P V (rotated contiguous b128 from vt_lds) ----
#pragma unroll
        for (int e = 0; e < 2; ++e) {
#pragma unroll
            for (int dt = 0; dt < 16; ++dt) {
                const int vb = (dt * 16 + n) * 64 + (((e * 4 + quad + n) & 7) << 3);
                short8 bv = *(const short8*)&vt_lds[vb];
                Oacc[0][dt] = MFMA32K(pf8[0][e], bv, Oacc[0][dt]);
                Oacc[1][dt] = MFMA32K(pf8[1][e], bv, Oacc[1][dt]);
            }
        }
    }

    // ---- epilogue: bf16 partials + cross-quad l reduction ----
    const size_t obase = (size_t)ly * N_Q * DV;
#pragma unroll
    for (int qt = 0; qt < 2; ++qt)
#pragma unroll
        for (int dt = 0; dt < 16; ++dt)
#pragma unroll
            for (int reg = 0; reg < 4; ++reg) {
                int gr = qrow0 + qt * 16 + quad * 4 + reg;
                Opart[obase + (size_t)gr * DV + dt * 16 + n] = f2bf(Oacc[qt][dt][reg]);
            }
#pragma unroll
    for (int qt = 0; qt < 2; ++qt) {
        float r = lrow[qt];
        r += __shfl_xor(r, 16);
        r += __shfl_xor(r, 32);
        if (quad == 0)
            Lpart[ly * N_Q + qrow0 + qt * 16 + n] = r;
    }
}

// ---------------------------------------------------------------------------
// Combine: out = (sum_c O_c) / (sum_c l_c).
// ---------------------------------------------------------------------------
__global__ __launch_bounds__(256) void combine_kernel(
    const unsigned short* __restrict__ Opart, const float* __restrict__ Lpart,
    float* __restrict__ out, int nsplit)
{
    const int row = blockIdx.x, d = threadIdx.x;
    float L = 0.f, o = 0.f;
    for (int c = 0; c < nsplit; ++c) {
        L += Lpart[c * N_Q + row];
        unsigned int b = Opart[((size_t)c * N_Q + row) * DV + d];
        o += __uint_as_float(b << 16);
    }
    out[(size_t)row * DV + d] = o / L;
}

// ---------------------------------------------------------------------------
extern "C" void kernel_launch(void* const* d_in, const int* in_sizes, int n_in,
                              void* d_out, int out_size, void* d_ws, size_t ws_size,
                              hipStream_t stream)
{
    const float* main_feat  = (const float*)d_in[0];
    const float* other_feat = (const float*)d_in[1];
    const float* fix_feat   = (const float*)d_in[2];
    const void*  mask       = d_in[3];
    const float* Wq         = (const float*)d_in[4];
    const float* bq         = (const float*)d_in[5];
    const float* Wk         = (const float*)d_in[6];
    const float* bk         = (const float*)d_in[7];
    float* out = (float*)d_out;

    char* ws = (char*)d_ws;
    unsigned short* Qw = (unsigned short*)(ws);                         // 2 MB
    unsigned short* Kw = (unsigned short*)(ws + (1ull << 21));          // 2 MB
    unsigned short* Vt = (unsigned short*)(ws + (2ull << 21));          // 4 MB
    unsigned long long* Mb = (unsigned long long*)(ws + (8ull << 20) + 1024);  // 8 MB
    float* Lpart = (float*)(ws + (16ull << 20) + 2048);

    const size_t base = (16ull << 20) + 2048;
    auto need = [&](int ns) {
        return base + (size_t)ns * N_Q * 4 + (size_t)ns * N_Q * DV * 2;
    };
    int nsplit = 1, lgNs = 0;
    if (ws_size >= need(8))      { nsplit = 8; lgNs = 3; }
    else if (ws_size >= need(4)) { nsplit = 4; lgNs = 2; }
    else if (ws_size >= need(2)) { nsplit = 2; lgNs = 1; }

    unsigned short* Opart = (unsigned short*)(Lpart + (size_t)nsplit * N_Q);

    hipLaunchKernelGGL(pack_mask_kernel, dim3(N_Q * MWORDS / 256), dim3(256), 0, stream,
                       mask, Mb);
    hipLaunchKernelGGL(proj_kernel, dim3(128, 2), dim3(256), 0, stream,
                       main_feat, Wq, bq, other_feat, Wk, bk, Qw, Kw);
    hipLaunchKernelGGL(build_vt_kernel, dim3(128, 4), dim3(256), 0, stream,
                       other_feat, fix_feat, Vt);
    hipLaunchKernelGGL(flash_kernel, dim3(64, nsplit), dim3(256), 0, stream,
                       Qw, Kw, Vt, Mb, Opart, Lpart, nsplit, lgNs);
    hipLaunchKernelGGL(combine_kernel, dim3(N_Q), dim3(256), 0, stream,
                       Opart, Lpart, out, nsplit);
}